// Round 7
// baseline (491.318 us; speedup 1.0000x reference)
//
#include <hip/hip_runtime.h>

// NaiveCustomLSTM: V block-diagonal (20 blocks of 32), U (nearly) diagonal.
// => 2560 independent 32-wide LSTMs (128 batch x 20 blocks), 512 steps.
//
// R14: kill the per-step LDS round trip. Model pinned by R11-R13:
// T_wave = max(L_chain, W x I_issue); L_chain ~= 1250 cyc dominated all
// rounds (per-wave step time identical at W=2.5 and W=1.25; Newton-rcp
// lengthened the chain and regressed). HW constants from VALUBusy
// accounting: v_pk_fma_f32 = 4 cyc issue (half rate), v_exp/v_rcp ~= 32
// busy cyc (wave64 trans). Largest removable chain term: h ds_write ->
// in-order pipe -> 8x ds_read_b128 -> lgkm drain (~300-400 cyc).
//
// Fix: broadcast h DIRECTLY from the live register via ds_bpermute_b32
// (crossbar only, no LDS write/read round trip): lanes 0-31 read lane k
// (unit A h[k]), lanes 32-63 read lane 32+k (unit B h[k]) using base addr
// (lane&32)*4 + offset:k*4 (k is an immediate in the unrolled MAC code).
// x likewise bpermuted from registers: 32-step chunks, lanes 0-31 hold
// batch-0 rows t=c*32+lane, lanes 32-63 batch-1 -> one bpermute serves
// both halves; addr reg +4 per step. LDS now prologue-only (weights).
// Per step: 34 bperm + 68 pk_fma + rcp tail. FP sequence byte-identical
// to R12 -> absmax must be exactly 2.441406e-4 (addressing self-check).
// Double-buffered x loads (v36/37 cur, v38/39 next), vmcnt(0) per chunk.

#define TT 512
#define HN 640
#define BN 128

typedef float f2 __attribute__((ext_vector_type(2)));
typedef unsigned int u32x4 __attribute__((ext_vector_type(4)));

__global__ __attribute__((amdgpu_flat_work_group_size(64, 64)))
void lstm_kernel(
    const float* __restrict__ x,
    const float* __restrict__ Ui, const float* __restrict__ Vi, const float* __restrict__ bi,
    const float* __restrict__ Uf, const float* __restrict__ Vf, const float* __restrict__ bf,
    const float* __restrict__ Uc, const float* __restrict__ Vc, const float* __restrict__ bc,
    const float* __restrict__ Uo, const float* __restrict__ Vo, const float* __restrict__ bo,
    float* __restrict__ out) {
  // LDS: weights only (prologue staging). 32 cols x 528B (132 floats; 4 per
  // k: {Bs*Vi, Bs*Vf, Bg*Vc, Bs*Vo}[k]; 528 stride avoids bank conflicts on
  // the prologue b128 reads).
  __shared__ __align__(16) float lds[4224];

  const int unit = blockIdx.x;   // 0..1279
  const int lane = threadIdx.x;  // 0..63
  const int j  = unit >> 6;      // hidden block 0..19
  const int bp = unit & 63;      // batch pair
  const int gp = lane >> 5;      // 0: batch 2bp ; 1: batch 2bp+1
  const int n  = lane & 31;
  const int col = j * 32 + n;
  const int b  = bp * 2 + gp;

  const float LOG2E = 1.44269504088896340736f;
  const float Bs = -LOG2E;        // sigmoid gates (i, f, o)
  const float Bg = -2.f * LOG2E;  // tanh gate (g)

  // Stage pre-scaled V-weight columns in LDS (lanes 0-31; same-wave DS
  // ordering makes them visible to the asm ds_reads, single wave per WG).
  if (lane < 32) {
    for (int k = 0; k < 32; ++k) {
      const int r = (j * 32 + k) * HN + col;
      lds[n * 132 + k * 4 + 0] = Bs * Vi[r];
      lds[n * 132 + k * 4 + 1] = Bs * Vf[r];
      lds[n * 132 + k * 4 + 2] = Bg * Vc[r];
      lds[n * 132 + k * 4 + 3] = Bs * Vo[r];
    }
  }

  // Effective input weights per gate (U mask structure), features f1, f2i.
  int f1 = 0, f2i = 0;
  if (j < 16) { f1 = f2i = j; if (j == 0) f2i = 1; else if (j == 2) f2i = 3; }
  auto uw = [&](const float* __restrict__ U, float& w1, float& w2) {
    w1 = 0.f; w2 = 0.f;
    if (j < 16) {
      w1 = U[j * HN + col];
      if (j == 0)      { w1 += U[16 * HN + col]; w2 = U[17 * HN + col]; }
      else if (j == 2) { w1 += U[18 * HN + col]; w2 = U[19 * HN + col]; }
    }
  };
  float wi1, wi2, wf1, wf2, wg1, wg2, wo1, wo2;
  uw(Ui, wi1, wi2); uw(Uf, wf1, wf2); uw(Uc, wg1, wg2); uw(Uo, wo1, wo2);
  const f2 w11IF = {Bs * wi1, Bs * wf1}, w21IF = {Bs * wi2, Bs * wf2};
  const f2 w11GO = {Bg * wg1, Bs * wo1}, w21GO = {Bg * wg2, Bs * wo2};
  const f2 bsIF  = {Bs * bi[col], Bs * bf[col]};
  const f2 bsGO  = {Bg * bc[col], Bs * bo[col]};

  const unsigned zb  = (unsigned)(unsigned long long)&lds[0];
  const unsigned wrd = zb + (unsigned)n * 528u;       // weight read addr
  const unsigned hbb = (unsigned)(lane & 32) * 4u;    // bperm base: 0 / 128

  // SRDs: x (bounds-checked; last-chunk prefetch may read OOB -> 0, unused)
  // and out (per-step h stores).
  u32x4 xsrd, osrd;
  { const unsigned long long a = (unsigned long long)x;
    xsrd.x = (unsigned)a; xsrd.y = (unsigned)(a >> 32);
    xsrd.z = (unsigned)(BN * TT * 16 * 4); xsrd.w = 0x00020000u; }
  { const unsigned long long a = (unsigned long long)out;
    osrd.x = (unsigned)a; osrd.y = (unsigned)(a >> 32);
    osrd.z = (unsigned)((BN * TT * HN + 2 * BN * HN) * 4); osrd.w = 0x00020000u; }

  unsigned voff  = (unsigned)((b * TT * HN + col) * 4);
  // Per-lane x row: this lane's batch, t = chunk*32 + (lane&31), feature f1.
  unsigned xvoff = (unsigned)(((b * TT + (lane & 31)) * 16 + f1) * 4);
  const int sfd  = (f2i - f1) * 4;

  float h = 0.f, c = 0.f;

  asm volatile(
    // ---- prologue: weights LDS->v[96:223]; x chunk-0 loads into v38/39 ----
    "s_waitcnt lgkmcnt(0)\n\t"
    "ds_read_b128 v[96:99],   %[wrd]\n\t"
    "ds_read_b128 v[100:103], %[wrd] offset:16\n\t"
    "ds_read_b128 v[104:107], %[wrd] offset:32\n\t"
    "ds_read_b128 v[108:111], %[wrd] offset:48\n\t"
    "ds_read_b128 v[112:115], %[wrd] offset:64\n\t"
    "ds_read_b128 v[116:119], %[wrd] offset:80\n\t"
    "ds_read_b128 v[120:123], %[wrd] offset:96\n\t"
    "ds_read_b128 v[124:127], %[wrd] offset:112\n\t"
    "ds_read_b128 v[128:131], %[wrd] offset:128\n\t"
    "ds_read_b128 v[132:135], %[wrd] offset:144\n\t"
    "ds_read_b128 v[136:139], %[wrd] offset:160\n\t"
    "ds_read_b128 v[140:143], %[wrd] offset:176\n\t"
    "ds_read_b128 v[144:147], %[wrd] offset:192\n\t"
    "ds_read_b128 v[148:151], %[wrd] offset:208\n\t"
    "ds_read_b128 v[152:155], %[wrd] offset:224\n\t"
    "ds_read_b128 v[156:159], %[wrd] offset:240\n\t"
    "ds_read_b128 v[160:163], %[wrd] offset:256\n\t"
    "ds_read_b128 v[164:167], %[wrd] offset:272\n\t"
    "ds_read_b128 v[168:171], %[wrd] offset:288\n\t"
    "ds_read_b128 v[172:175], %[wrd] offset:304\n\t"
    "ds_read_b128 v[176:179], %[wrd] offset:320\n\t"
    "ds_read_b128 v[180:183], %[wrd] offset:336\n\t"
    "ds_read_b128 v[184:187], %[wrd] offset:352\n\t"
    "ds_read_b128 v[188:191], %[wrd] offset:368\n\t"
    "ds_read_b128 v[192:195], %[wrd] offset:384\n\t"
    "ds_read_b128 v[196:199], %[wrd] offset:400\n\t"
    "ds_read_b128 v[200:203], %[wrd] offset:416\n\t"
    "ds_read_b128 v[204:207], %[wrd] offset:432\n\t"
    "ds_read_b128 v[208:211], %[wrd] offset:448\n\t"
    "ds_read_b128 v[212:215], %[wrd] offset:464\n\t"
    "ds_read_b128 v[216:219], %[wrd] offset:480\n\t"
    "ds_read_b128 v[220:223], %[wrd] offset:496\n\t"
    "buffer_load_dword v38, %[xvoff], %[xsrd], 0 offen\n\t"
    "buffer_load_dword v39, %[xvoff], %[xsrd], %[sfd] offen\n\t"
    "s_waitcnt lgkmcnt(0)\n\t"
    "s_mov_b32 s21, 16\n\t"
    "Lchunk%=:\n\t"
    // rotate double-buffered x; prefetch next 32-step chunk
    "s_waitcnt vmcnt(0)\n\t"
    "v_mov_b32 v36, v38\n\t"
    "v_mov_b32 v37, v39\n\t"
    "v_add_u32 %[xvoff], 0x800, %[xvoff]\n\t"
    "buffer_load_dword v38, %[xvoff], %[xsrd], 0 offen\n\t"
    "buffer_load_dword v39, %[xvoff], %[xsrd], %[sfd] offen\n\t"
    "v_mov_b32 v33, %[hbb]\n\t"
    "s_mov_b32 s20, 32\n\t"
    "Lstep%=:\n\t"
    // x select (step s via v33) + h broadcast k=0..7 straight from %[h]
    "ds_bpermute_b32 v88, v33, v36\n\t"
    "ds_bpermute_b32 v89, v33, v37\n\t"
    "ds_bpermute_b32 v48, %[hbb], %[h] offset:0\n\t"
    "ds_bpermute_b32 v50, %[hbb], %[h] offset:4\n\t"
    "ds_bpermute_b32 v52, %[hbb], %[h] offset:8\n\t"
    "ds_bpermute_b32 v54, %[hbb], %[h] offset:12\n\t"
    "ds_bpermute_b32 v56, %[hbb], %[h] offset:16\n\t"
    "ds_bpermute_b32 v58, %[hbb], %[h] offset:20\n\t"
    "ds_bpermute_b32 v60, %[hbb], %[h] offset:24\n\t"
    "ds_bpermute_b32 v62, %[hbb], %[h] offset:28\n\t"
    "v_add_u32 v33, 4, v33\n\t"
    "s_waitcnt lgkmcnt(8)\n\t"
    // seeds: accIF0 = bsIF + x1*w11IF + x2*w21IF ; accGO0 likewise
    "v_pk_fma_f32 v[40:41], v[88:89], %[w11IF], %[bsIF] op_sel:[0,0,0] op_sel_hi:[0,1,1]\n\t"
    "v_pk_fma_f32 v[44:45], v[88:89], %[w11GO], %[bsGO] op_sel:[0,0,0] op_sel_hi:[0,1,1]\n\t"
    "v_pk_fma_f32 v[40:41], v[88:89], %[w21IF], v[40:41] op_sel:[1,0,0] op_sel_hi:[1,1,1]\n\t"
    "v_pk_fma_f32 v[44:45], v[88:89], %[w21GO], v[44:45] op_sel:[1,0,0] op_sel_hi:[1,1,1]\n\t"
    "v_mov_b32 v42, 0\n\t"
    "v_mov_b32 v43, 0\n\t"
    "v_mov_b32 v46, 0\n\t"
    "v_mov_b32 v47, 0\n\t"
    // 64 MACs, even k -> chains v40/44, odd k -> v42/46; h[k] broadcast to
    // both halves via op_sel (only the even reg of each ring pair is read).
    "s_waitcnt lgkmcnt(4)\n\t"
    "v_pk_fma_f32 v[40:41], v[96:97],   v[48:49], v[40:41] op_sel:[0,0,0] op_sel_hi:[1,0,1]\n\t"
    "v_pk_fma_f32 v[44:45], v[98:99],   v[48:49], v[44:45] op_sel:[0,0,0] op_sel_hi:[1,0,1]\n\t"
    "v_pk_fma_f32 v[42:43], v[100:101], v[50:51], v[42:43] op_sel:[0,0,0] op_sel_hi:[1,0,1]\n\t"
    "v_pk_fma_f32 v[46:47], v[102:103], v[50:51], v[46:47] op_sel:[0,0,0] op_sel_hi:[1,0,1]\n\t"
    "v_pk_fma_f32 v[40:41], v[104:105], v[52:53], v[40:41] op_sel:[0,0,0] op_sel_hi:[1,0,1]\n\t"
    "v_pk_fma_f32 v[44:45], v[106:107], v[52:53], v[44:45] op_sel:[0,0,0] op_sel_hi:[1,0,1]\n\t"
    "v_pk_fma_f32 v[42:43], v[108:109], v[54:55], v[42:43] op_sel:[0,0,0] op_sel_hi:[1,0,1]\n\t"
    "v_pk_fma_f32 v[46:47], v[110:111], v[54:55], v[46:47] op_sel:[0,0,0] op_sel_hi:[1,0,1]\n\t"
    "ds_bpermute_b32 v48, %[hbb], %[h] offset:32\n\t"
    "ds_bpermute_b32 v50, %[hbb], %[h] offset:36\n\t"
    "ds_bpermute_b32 v52, %[hbb], %[h] offset:40\n\t"
    "ds_bpermute_b32 v54, %[hbb], %[h] offset:44\n\t"
    "s_waitcnt lgkmcnt(4)\n\t"
    "v_pk_fma_f32 v[40:41], v[112:113], v[56:57], v[40:41] op_sel:[0,0,0] op_sel_hi:[1,0,1]\n\t"
    "v_pk_fma_f32 v[44:45], v[114:115], v[56:57], v[44:45] op_sel:[0,0,0] op_sel_hi:[1,0,1]\n\t"
    "v_pk_fma_f32 v[42:43], v[116:117], v[58:59], v[42:43] op_sel:[0,0,0] op_sel_hi:[1,0,1]\n\t"
    "v_pk_fma_f32 v[46:47], v[118:119], v[58:59], v[46:47] op_sel:[0,0,0] op_sel_hi:[1,0,1]\n\t"
    "v_pk_fma_f32 v[40:41], v[120:121], v[60:61], v[40:41] op_sel:[0,0,0] op_sel_hi:[1,0,1]\n\t"
    "v_pk_fma_f32 v[44:45], v[122:123], v[60:61], v[44:45] op_sel:[0,0,0] op_sel_hi:[1,0,1]\n\t"
    "v_pk_fma_f32 v[42:43], v[124:125], v[62:63], v[42:43] op_sel:[0,0,0] op_sel_hi:[1,0,1]\n\t"
    "v_pk_fma_f32 v[46:47], v[126:127], v[62:63], v[46:47] op_sel:[0,0,0] op_sel_hi:[1,0,1]\n\t"
    "ds_bpermute_b32 v56, %[hbb], %[h] offset:48\n\t"
    "ds_bpermute_b32 v58, %[hbb], %[h] offset:52\n\t"
    "ds_bpermute_b32 v60, %[hbb], %[h] offset:56\n\t"
    "ds_bpermute_b32 v62, %[hbb], %[h] offset:60\n\t"
    "s_waitcnt lgkmcnt(4)\n\t"
    "v_pk_fma_f32 v[40:41], v[128:129], v[48:49], v[40:41] op_sel:[0,0,0] op_sel_hi:[1,0,1]\n\t"
    "v_pk_fma_f32 v[44:45], v[130:131], v[48:49], v[44:45] op_sel:[0,0,0] op_sel_hi:[1,0,1]\n\t"
    "v_pk_fma_f32 v[42:43], v[132:133], v[50:51], v[42:43] op_sel:[0,0,0] op_sel_hi:[1,0,1]\n\t"
    "v_pk_fma_f32 v[46:47], v[134:135], v[50:51], v[46:47] op_sel:[0,0,0] op_sel_hi:[1,0,1]\n\t"
    "v_pk_fma_f32 v[40:41], v[136:137], v[52:53], v[40:41] op_sel:[0,0,0] op_sel_hi:[1,0,1]\n\t"
    "v_pk_fma_f32 v[44:45], v[138:139], v[52:53], v[44:45] op_sel:[0,0,0] op_sel_hi:[1,0,1]\n\t"
    "v_pk_fma_f32 v[42:43], v[140:141], v[54:55], v[42:43] op_sel:[0,0,0] op_sel_hi:[1,0,1]\n\t"
    "v_pk_fma_f32 v[46:47], v[142:143], v[54:55], v[46:47] op_sel:[0,0,0] op_sel_hi:[1,0,1]\n\t"
    "ds_bpermute_b32 v48, %[hbb], %[h] offset:64\n\t"
    "ds_bpermute_b32 v50, %[hbb], %[h] offset:68\n\t"
    "ds_bpermute_b32 v52, %[hbb], %[h] offset:72\n\t"
    "ds_bpermute_b32 v54, %[hbb], %[h] offset:76\n\t"
    "s_waitcnt lgkmcnt(4)\n\t"
    "v_pk_fma_f32 v[40:41], v[144:145], v[56:57], v[40:41] op_sel:[0,0,0] op_sel_hi:[1,0,1]\n\t"
    "v_pk_fma_f32 v[44:45], v[146:147], v[56:57], v[44:45] op_sel:[0,0,0] op_sel_hi:[1,0,1]\n\t"
    "v_pk_fma_f32 v[42:43], v[148:149], v[58:59], v[42:43] op_sel:[0,0,0] op_sel_hi:[1,0,1]\n\t"
    "v_pk_fma_f32 v[46:47], v[150:151], v[58:59], v[46:47] op_sel:[0,0,0] op_sel_hi:[1,0,1]\n\t"
    "v_pk_fma_f32 v[40:41], v[152:153], v[60:61], v[40:41] op_sel:[0,0,0] op_sel_hi:[1,0,1]\n\t"
    "v_pk_fma_f32 v[44:45], v[154:155], v[60:61], v[44:45] op_sel:[0,0,0] op_sel_hi:[1,0,1]\n\t"
    "v_pk_fma_f32 v[42:43], v[156:157], v[62:63], v[42:43] op_sel:[0,0,0] op_sel_hi:[1,0,1]\n\t"
    "v_pk_fma_f32 v[46:47], v[158:159], v[62:63], v[46:47] op_sel:[0,0,0] op_sel_hi:[1,0,1]\n\t"
    "ds_bpermute_b32 v56, %[hbb], %[h] offset:80\n\t"
    "ds_bpermute_b32 v58, %[hbb], %[h] offset:84\n\t"
    "ds_bpermute_b32 v60, %[hbb], %[h] offset:88\n\t"
    "ds_bpermute_b32 v62, %[hbb], %[h] offset:92\n\t"
    "s_waitcnt lgkmcnt(4)\n\t"
    "v_pk_fma_f32 v[40:41], v[160:161], v[48:49], v[40:41] op_sel:[0,0,0] op_sel_hi:[1,0,1]\n\t"
    "v_pk_fma_f32 v[44:45], v[162:163], v[48:49], v[44:45] op_sel:[0,0,0] op_sel_hi:[1,0,1]\n\t"
    "v_pk_fma_f32 v[42:43], v[164:165], v[50:51], v[42:43] op_sel:[0,0,0] op_sel_hi:[1,0,1]\n\t"
    "v_pk_fma_f32 v[46:47], v[166:167], v[50:51], v[46:47] op_sel:[0,0,0] op_sel_hi:[1,0,1]\n\t"
    "v_pk_fma_f32 v[40:41], v[168:169], v[52:53], v[40:41] op_sel:[0,0,0] op_sel_hi:[1,0,1]\n\t"
    "v_pk_fma_f32 v[44:45], v[170:171], v[52:53], v[44:45] op_sel:[0,0,0] op_sel_hi:[1,0,1]\n\t"
    "v_pk_fma_f32 v[42:43], v[172:173], v[54:55], v[42:43] op_sel:[0,0,0] op_sel_hi:[1,0,1]\n\t"
    "v_pk_fma_f32 v[46:47], v[174:175], v[54:55], v[46:47] op_sel:[0,0,0] op_sel_hi:[1,0,1]\n\t"
    "ds_bpermute_b32 v48, %[hbb], %[h] offset:96\n\t"
    "ds_bpermute_b32 v50, %[hbb], %[h] offset:100\n\t"
    "ds_bpermute_b32 v52, %[hbb], %[h] offset:104\n\t"
    "ds_bpermute_b32 v54, %[hbb], %[h] offset:108\n\t"
    "s_waitcnt lgkmcnt(4)\n\t"
    "v_pk_fma_f32 v[40:41], v[176:177], v[56:57], v[40:41] op_sel:[0,0,0] op_sel_hi:[1,0,1]\n\t"
    "v_pk_fma_f32 v[44:45], v[178:179], v[56:57], v[44:45] op_sel:[0,0,0] op_sel_hi:[1,0,1]\n\t"
    "v_pk_fma_f32 v[42:43], v[180:181], v[58:59], v[42:43] op_sel:[0,0,0] op_sel_hi:[1,0,1]\n\t"
    "v_pk_fma_f32 v[46:47], v[182:183], v[58:59], v[46:47] op_sel:[0,0,0] op_sel_hi:[1,0,1]\n\t"
    "v_pk_fma_f32 v[40:41], v[184:185], v[60:61], v[40:41] op_sel:[0,0,0] op_sel_hi:[1,0,1]\n\t"
    "v_pk_fma_f32 v[44:45], v[186:187], v[60:61], v[44:45] op_sel:[0,0,0] op_sel_hi:[1,0,1]\n\t"
    "v_pk_fma_f32 v[42:43], v[188:189], v[62:63], v[42:43] op_sel:[0,0,0] op_sel_hi:[1,0,1]\n\t"
    "v_pk_fma_f32 v[46:47], v[190:191], v[62:63], v[46:47] op_sel:[0,0,0] op_sel_hi:[1,0,1]\n\t"
    "ds_bpermute_b32 v56, %[hbb], %[h] offset:112\n\t"
    "ds_bpermute_b32 v58, %[hbb], %[h] offset:116\n\t"
    "ds_bpermute_b32 v60, %[hbb], %[h] offset:120\n\t"
    "ds_bpermute_b32 v62, %[hbb], %[h] offset:124\n\t"
    "s_waitcnt lgkmcnt(4)\n\t"
    "v_pk_fma_f32 v[40:41], v[192:193], v[48:49], v[40:41] op_sel:[0,0,0] op_sel_hi:[1,0,1]\n\t"
    "v_pk_fma_f32 v[44:45], v[194:195], v[48:49], v[44:45] op_sel:[0,0,0] op_sel_hi:[1,0,1]\n\t"
    "v_pk_fma_f32 v[42:43], v[196:197], v[50:51], v[42:43] op_sel:[0,0,0] op_sel_hi:[1,0,1]\n\t"
    "v_pk_fma_f32 v[46:47], v[198:199], v[50:51], v[46:47] op_sel:[0,0,0] op_sel_hi:[1,0,1]\n\t"
    "v_pk_fma_f32 v[40:41], v[200:201], v[52:53], v[40:41] op_sel:[0,0,0] op_sel_hi:[1,0,1]\n\t"
    "v_pk_fma_f32 v[44:45], v[202:203], v[52:53], v[44:45] op_sel:[0,0,0] op_sel_hi:[1,0,1]\n\t"
    "v_pk_fma_f32 v[42:43], v[204:205], v[54:55], v[42:43] op_sel:[0,0,0] op_sel_hi:[1,0,1]\n\t"
    "v_pk_fma_f32 v[46:47], v[206:207], v[54:55], v[46:47] op_sel:[0,0,0] op_sel_hi:[1,0,1]\n\t"
    "s_waitcnt lgkmcnt(0)\n\t"
    "v_pk_fma_f32 v[40:41], v[208:209], v[56:57], v[40:41] op_sel:[0,0,0] op_sel_hi:[1,0,1]\n\t"
    "v_pk_fma_f32 v[44:45], v[210:211], v[56:57], v[44:45] op_sel:[0,0,0] op_sel_hi:[1,0,1]\n\t"
    "v_pk_fma_f32 v[42:43], v[212:213], v[58:59], v[42:43] op_sel:[0,0,0] op_sel_hi:[1,0,1]\n\t"
    "v_pk_fma_f32 v[46:47], v[214:215], v[58:59], v[46:47] op_sel:[0,0,0] op_sel_hi:[1,0,1]\n\t"
    "v_pk_fma_f32 v[40:41], v[216:217], v[60:61], v[40:41] op_sel:[0,0,0] op_sel_hi:[1,0,1]\n\t"
    "v_pk_fma_f32 v[44:45], v[218:219], v[60:61], v[44:45] op_sel:[0,0,0] op_sel_hi:[1,0,1]\n\t"
    "v_pk_fma_f32 v[42:43], v[220:221], v[62:63], v[42:43] op_sel:[0,0,0] op_sel_hi:[1,0,1]\n\t"
    "v_pk_fma_f32 v[46:47], v[222:223], v[62:63], v[46:47] op_sel:[0,0,0] op_sel_hi:[1,0,1]\n\t"
    // reduce + activations (identical FP sequence to R12's rcp tail)
    "v_pk_add_f32 v[40:41], v[40:41], v[42:43]\n\t"
    "v_pk_add_f32 v[44:45], v[44:45], v[46:47]\n\t"
    "v_exp_f32 v80, v40\n\t"
    "v_exp_f32 v81, v41\n\t"
    "v_exp_f32 v82, v44\n\t"
    "v_exp_f32 v83, v45\n\t"
    "v_add_f32 v80, 1.0, v80\n\t"
    "v_add_f32 v81, 1.0, v81\n\t"
    "v_add_f32 v82, 1.0, v82\n\t"
    "v_add_f32 v83, 1.0, v83\n\t"
    "v_rcp_f32 v80, v80\n\t"              // sig(i)
    "v_rcp_f32 v81, v81\n\t"              // sig(f)
    "v_rcp_f32 v82, v82\n\t"              // -> tanh(g)
    "v_rcp_f32 v83, v83\n\t"              // sig(o)
    "v_fma_f32 v82, 2.0, v82, -1.0\n\t"   // tanh(g)
    "v_mul_f32 v84, v80, v82\n\t"         // sig(i)*tanh(g)
    "v_fma_f32 %[c], v81, %[c], v84\n\t"  // c = sig(f)*c + sig(i)*tanh(g)
    "v_mul_f32 v85, 0xc038aa3b, %[c]\n\t" // -2*log2e * c
    "v_exp_f32 v85, v85\n\t"
    "s_nop 1\n\t"
    "v_add_f32 v85, 1.0, v85\n\t"
    "v_rcp_f32 v85, v85\n\t"
    "s_nop 1\n\t"
    "v_fma_f32 v85, 2.0, v85, -1.0\n\t"   // tanh(c)
    "v_mul_f32 %[h], v83, v85\n\t"        // h = sig(o)*tanh(c)
    "buffer_store_dword %[h], %[voff], %[osrd], 0 offen\n\t"
    "v_add_u32 %[voff], 0xa00, %[voff]\n\t"
    "s_sub_u32 s20, s20, 1\n\t"
    "s_cmp_lg_u32 s20, 0\n\t"
    "s_cbranch_scc1 Lstep%=\n\t"
    "s_sub_u32 s21, s21, 1\n\t"
    "s_cmp_lg_u32 s21, 0\n\t"
    "s_cbranch_scc1 Lchunk%=\n\t"
    : [h]"+v"(h), [c]"+v"(c), [voff]"+v"(voff), [xvoff]"+v"(xvoff)
    : [hbb]"v"(hbb), [wrd]"v"(wrd),
      [w11IF]"v"(w11IF), [w21IF]"v"(w21IF), [bsIF]"v"(bsIF),
      [w11GO]"v"(w11GO), [w21GO]"v"(w21GO), [bsGO]"v"(bsGO),
      [xsrd]"s"(xsrd), [osrd]"s"(osrd), [sfd]"s"(sfd)
    : "memory", "scc", "s20", "s21",
      "v33","v36","v37","v38","v39",
      "v40","v41","v42","v43","v44","v45","v46","v47",
      "v48","v49","v50","v51","v52","v53","v54","v55",
      "v56","v57","v58","v59","v60","v61","v62","v63",
      "v80","v81","v82","v83","v84","v85","v88","v89",
      "v96","v97","v98","v99","v100","v101","v102","v103",
      "v104","v105","v106","v107","v108","v109","v110","v111",
      "v112","v113","v114","v115","v116","v117","v118","v119",
      "v120","v121","v122","v123","v124","v125","v126","v127",
      "v128","v129","v130","v131","v132","v133","v134","v135",
      "v136","v137","v138","v139","v140","v141","v142","v143",
      "v144","v145","v146","v147","v148","v149","v150","v151",
      "v152","v153","v154","v155","v156","v157","v158","v159",
      "v160","v161","v162","v163","v164","v165","v166","v167",
      "v168","v169","v170","v171","v172","v173","v174","v175",
      "v176","v177","v178","v179","v180","v181","v182","v183",
      "v184","v185","v186","v187","v188","v189","v190","v191",
      "v192","v193","v194","v195","v196","v197","v198","v199",
      "v200","v201","v202","v203","v204","v205","v206","v207",
      "v208","v209","v210","v211","v212","v213","v214","v215",
      "v216","v217","v218","v219","v220","v221","v222","v223");

  out[BN * TT * HN + b * HN + col] = h;             // h_t
  out[BN * TT * HN + BN * HN + b * HN + col] = c;   // c_t
}

extern "C" void kernel_launch(void* const* d_in, const int* in_sizes, int n_in,
                              void* d_out, int out_size, void* d_ws, size_t ws_size,
                              hipStream_t stream) {
  (void)in_sizes; (void)n_in; (void)d_ws; (void)ws_size; (void)out_size;
  const float* x  = (const float*)d_in[0];
  const float* Ui = (const float*)d_in[1];
  const float* Vi = (const float*)d_in[2];
  const float* bi = (const float*)d_in[3];
  const float* Uf = (const float*)d_in[4];
  const float* Vf = (const float*)d_in[5];
  const float* bf = (const float*)d_in[6];
  const float* Uc = (const float*)d_in[7];
  const float* Vc = (const float*)d_in[8];
  const float* bc = (const float*)d_in[9];
  const float* Uo = (const float*)d_in[10];
  const float* Vo = (const float*)d_in[11];
  const float* bo = (const float*)d_in[12];
  float* out = (float*)d_out;

  dim3 grid(1280);  // 20 blocks x 64 batch-pairs; 2 units per wave
  dim3 block(64);
  hipLaunchKernelGGL(lstm_kernel, grid, block, 0, stream,
                     x, Ui, Vi, bi, Uf, Vf, bf, Uc, Vc, bc, Uo, Vo, bo, out);
}

// Round 8
// 435.178 us; speedup vs baseline: 1.1290x; 1.1290x over previous
//
#include <hip/hip_runtime.h>

// NaiveCustomLSTM: V block-diagonal (20 blocks of 32), U (nearly) diagonal.
// => 2560 independent 32-wide LSTMs (128 batch x 20 blocks), 512 steps.
//
// R15: TWO ANTI-PHASED units per wave. R11-R14 pinned the model
// T_wave = max(L_chain, W*I_issue) with L_chain ~1250 cyc (DS broadcast
// round trip + MAC chain + trans tail) dominating at both W=2.5 and 1.25;
// chain-shortening attempts all failed (R13 Newton regressed, R14 bpermute
// broadcast regressed: 34 DS ops/step >> 10, DS pipe is the cost not the
// round trip). So: HIDE the chain. Each wave runs 2 units (same j-block,
// batches 2bp/2bp+1) as two independent instruction streams, hand-braided:
// unit A's h-broadcast (ds_write + 8x b128, the R12-proven mechanism) is in
// flight during unit B's MACs and vice versa; A's serial tail-end braids
// with B's tail-head. Per-phase layout = R11 (proven): lanes 0-31 = gates
// {i,f} for col n, lanes 32-63 = {g,o}; gates packed in pk halves -> 32
// v_pk_fma_f32 per phase per step; weights per lane = 64 regs SHARED by
// both phases. x via ds_bpermute from chunk regs (R14-proven addressing).
// 8 bpermutes/step total. Seeds added after the MAC chains (FP grouping
// shifts vs R11 -> absmax ~2-5e-4; R13's 4.88e-4 passed tolerance).

#define TT 512
#define HN 640
#define BN 128

typedef float f2 __attribute__((ext_vector_type(2)));
typedef unsigned int u32x4 __attribute__((ext_vector_type(4)));

__global__ __attribute__((amdgpu_flat_work_group_size(64, 64)))
void lstm_kernel(
    const float* __restrict__ x,
    const float* __restrict__ Ui, const float* __restrict__ Vi, const float* __restrict__ bi,
    const float* __restrict__ Uf, const float* __restrict__ Vf, const float* __restrict__ bf,
    const float* __restrict__ Uc, const float* __restrict__ Vc, const float* __restrict__ bc,
    const float* __restrict__ Uo, const float* __restrict__ Vo, const float* __restrict__ bo,
    float* __restrict__ out) {
  // LDS (floats): [0..4351] weights, 64 lanes x 68 stride (64 used: f2
  // {w_g1[k], w_g2[k]} k=0..31; 272B stride keeps b128 alignment).
  // [4352..4415] h buffer A; [4416..4479] h buffer B.
  __shared__ __align__(16) float lds[4480];

  const int unit = blockIdx.x;   // 0..1279
  const int lane = threadIdx.x;  // 0..63
  const int j  = unit >> 6;      // hidden block 0..19
  const int bp = unit & 63;      // batch pair
  const int gp = lane >> 5;      // 0: gates {i,f} ; 1: gates {g,o}
  const int n  = lane & 31;
  const int col = j * 32 + n;
  const int bA = bp * 2, bB = bp * 2 + 1;

  const float LOG2E = 1.44269504088896340736f;
  const float Bs = -LOG2E;        // sigmoid scale
  const float Bg = -2.f * LOG2E;  // tanh scale

  // Stage pre-scaled V-weight columns: lane<32 -> {Bs*Vi, Bs*Vf}[k],
  // lane>=32 -> {Bg*Vc, Bs*Vo}[k], col = j*32 + (lane&31).
  {
    const float* W1 = (lane < 32) ? Vi : Vc;
    const float* W2 = (lane < 32) ? Vf : Vo;
    const float s1 = (lane < 32) ? Bs : Bg;
    for (int k = 0; k < 32; ++k) {
      const int r = (j * 32 + k) * HN + col;
      lds[lane * 68 + 2 * k]     = s1 * W1[r];
      lds[lane * 68 + 2 * k + 1] = Bs * W2[r];
    }
  }

  // U mask structure -> features f1, f2i and effective input weights.
  int f1 = 0, f2i = 0;
  if (j < 16) { f1 = f2i = j; if (j == 0) f2i = 1; else if (j == 2) f2i = 3; }
  auto uw = [&](const float* __restrict__ U, float& w1, float& w2) {
    w1 = 0.f; w2 = 0.f;
    if (j < 16) {
      w1 = U[j * HN + col];
      if (j == 0)      { w1 += U[16 * HN + col]; w2 = U[17 * HN + col]; }
      else if (j == 2) { w1 += U[18 * HN + col]; w2 = U[19 * HN + col]; }
    }
  };
  float a1w, a2w, b1w, b2w;
  uw(gp ? Uc : Ui, a1w, a2w);   // gate1 (i or g)
  uw(gp ? Uo : Uf, b1w, b2w);   // gate2 (f or o)
  const float B1 = gp ? Bg : Bs;
  const f2 w11P = {B1 * a1w, Bs * b1w};
  const f2 w21P = {B1 * a2w, Bs * b2w};
  const f2 bsP  = {B1 * (gp ? bc[col] : bi[col]), Bs * (gp ? bo[col] : bf[col])};
  const float Ac1 = gp ? 2.f : 1.f;
  const float Cc1 = gp ? -1.f : 0.f;

  const unsigned zb = (unsigned)(unsigned long long)&lds[0];
  const unsigned wrd    = zb + (unsigned)lane * 272u;
  const unsigned hrdA   = zb + 17408u;
  const unsigned hrdB   = zb + 17664u;
  const unsigned laddrA = hrdA + (unsigned)lane * 4u;
  const unsigned laddrB = hrdB + (unsigned)lane * 4u;
  const unsigned swz    = (unsigned)((lane ^ 32) & 63) * 4u;

  u32x4 xsrd, osrd;
  { const unsigned long long a = (unsigned long long)x;
    xsrd.x = (unsigned)a; xsrd.y = (unsigned)(a >> 32);
    xsrd.z = (unsigned)(BN * TT * 16 * 4); xsrd.w = 0x00020000u; }
  { const unsigned long long a = (unsigned long long)out;
    osrd.x = (unsigned)a; osrd.y = (unsigned)(a >> 32);
    osrd.z = (unsigned)((BN * TT * HN + 2 * BN * HN) * 4); osrd.w = 0x00020000u; }

  // Per-step h stores: valid lanes 0-31; hi lanes OOB -> dropped by SRD.
  unsigned voffA = (lane < 32) ? (unsigned)((bA * TT * HN + col) * 4) : 0x60000000u;
  unsigned voffB = (lane < 32) ? (unsigned)((bB * TT * HN + col) * 4) : 0x60000000u;
  // Per-lane x rows: t = chunk*64 + lane, feature f1 (f2 via sfd offset).
  unsigned xvA = (unsigned)(((bA * TT + lane) * 16 + f1) * 4);
  unsigned xvB = (unsigned)(((bB * TT + lane) * 16 + f1) * 4);
  const int sfd = (f2i - f1) * 4;

  float hA = 0.f, cA = 0.f, hB = 0.f, cB = 0.f;

#define AMAC(M, WE, WO, HP) \
    "v_pk_fma_f32 v[40:41], v[" #WE "], v[" #HP "], v[40:41] op_sel:[0,0,0] op_sel_hi:[1,0,1]\n\t" \
    "v_pk_fma_f32 v[42:43], v[" #WO "], v[" #HP "], v[42:43] op_sel:[0,1,0] op_sel_hi:[1,1,1]\n\t"
#define BMAC(M, WE, WO, HP) \
    "v_pk_fma_f32 v[44:45], v[" #WE "], v[" #HP "], v[44:45] op_sel:[0,0,0] op_sel_hi:[1,0,1]\n\t" \
    "v_pk_fma_f32 v[46:47], v[" #WO "], v[" #HP "], v[46:47] op_sel:[0,1,0] op_sel_hi:[1,1,1]\n\t"

  asm volatile(
    // ===== prologue =====
    "s_waitcnt lgkmcnt(0)\n\t"
    "ds_read_b128 v[96:99],   %[wrd]\n\t"
    "ds_read_b128 v[100:103], %[wrd] offset:16\n\t"
    "ds_read_b128 v[104:107], %[wrd] offset:32\n\t"
    "ds_read_b128 v[108:111], %[wrd] offset:48\n\t"
    "ds_read_b128 v[112:115], %[wrd] offset:64\n\t"
    "ds_read_b128 v[116:119], %[wrd] offset:80\n\t"
    "ds_read_b128 v[120:123], %[wrd] offset:96\n\t"
    "ds_read_b128 v[124:127], %[wrd] offset:112\n\t"
    "ds_read_b128 v[128:131], %[wrd] offset:128\n\t"
    "ds_read_b128 v[132:135], %[wrd] offset:144\n\t"
    "ds_read_b128 v[136:139], %[wrd] offset:160\n\t"
    "ds_read_b128 v[140:143], %[wrd] offset:176\n\t"
    "ds_read_b128 v[144:147], %[wrd] offset:192\n\t"
    "ds_read_b128 v[148:151], %[wrd] offset:208\n\t"
    "ds_read_b128 v[152:155], %[wrd] offset:224\n\t"
    "ds_read_b128 v[156:159], %[wrd] offset:240\n\t"
    // x chunk 0 (cur) + chunk 1 (next)
    "buffer_load_dword v24, %[xvA], %[xsrd], 0 offen\n\t"
    "buffer_load_dword v25, %[xvA], %[xsrd], %[sfd] offen\n\t"
    "buffer_load_dword v26, %[xvB], %[xsrd], 0 offen\n\t"
    "buffer_load_dword v27, %[xvB], %[xsrd], %[sfd] offen\n\t"
    "v_add_u32 %[xvA], 0x1000, %[xvA]\n\t"
    "v_add_u32 %[xvB], 0x1000, %[xvB]\n\t"
    "buffer_load_dword v28, %[xvA], %[xsrd], 0 offen\n\t"
    "buffer_load_dword v29, %[xvA], %[xsrd], %[sfd] offen\n\t"
    "buffer_load_dword v30, %[xvB], %[xsrd], 0 offen\n\t"
    "buffer_load_dword v31, %[xvB], %[xsrd], %[sfd] offen\n\t"
    "s_waitcnt lgkmcnt(0)\n\t"            // weights resident
    // initial h groups (h = 0): FIFO = [Agrp(9), Bgrp(9)]
    "ds_write_b32 %[laddrA], %[hA]\n\t"
    "ds_read_b128 v[48:51], %[hrdA]\n\t"
    "ds_read_b128 v[52:55], %[hrdA] offset:16\n\t"
    "ds_read_b128 v[56:59], %[hrdA] offset:32\n\t"
    "ds_read_b128 v[60:63], %[hrdA] offset:48\n\t"
    "ds_read_b128 v[64:67], %[hrdA] offset:64\n\t"
    "ds_read_b128 v[68:71], %[hrdA] offset:80\n\t"
    "ds_read_b128 v[72:75], %[hrdA] offset:96\n\t"
    "ds_read_b128 v[76:79], %[hrdA] offset:112\n\t"
    "ds_write_b32 %[laddrB], %[hB]\n\t"
    "ds_read_b128 v[160:163], %[hrdB]\n\t"
    "ds_read_b128 v[164:167], %[hrdB] offset:16\n\t"
    "ds_read_b128 v[168:171], %[hrdB] offset:32\n\t"
    "ds_read_b128 v[172:175], %[hrdB] offset:48\n\t"
    "ds_read_b128 v[176:179], %[hrdB] offset:64\n\t"
    "ds_read_b128 v[180:183], %[hrdB] offset:80\n\t"
    "ds_read_b128 v[184:187], %[hrdB] offset:96\n\t"
    "ds_read_b128 v[188:191], %[hrdB] offset:112\n\t"
    "v_mov_b32 v33, 0\n\t"
    "s_mov_b32 s21, 8\n\t"
    "s_waitcnt vmcnt(4)\n\t"              // cur x resident
    "Louter%=:\n\t"
    "s_mov_b32 s20, 64\n\t"
    "Lbody%=:\n\t"
    // ---- A: wait ring, issue x-selects, MACs ----
    "s_waitcnt lgkmcnt(9)\n\t"            // A-grp done (B-grp 9 in flight)
    "ds_bpermute_b32 v88, v33, v24\n\t"   // xA f1
    "ds_bpermute_b32 v89, v33, v25\n\t"   // xA f2
    "v_pk_mul_f32 v[40:41], v[96:97], v[48:49] op_sel:[0,0] op_sel_hi:[1,0]\n\t"
    "v_pk_mul_f32 v[42:43], v[98:99], v[48:49] op_sel:[0,1] op_sel_hi:[1,1]\n\t"
    AMAC(1,  100:101, 102:103, 50:51)
    AMAC(2,  104:105, 106:107, 52:53)
    AMAC(3,  108:109, 110:111, 54:55)
    AMAC(4,  112:113, 114:115, 56:57)
    AMAC(5,  116:117, 118:119, 58:59)
    AMAC(6,  120:121, 122:123, 60:61)
    AMAC(7,  124:125, 126:127, 62:63)
    AMAC(8,  128:129, 130:131, 64:65)
    AMAC(9,  132:133, 134:135, 66:67)
    AMAC(10, 136:137, 138:139, 68:69)
    AMAC(11, 140:141, 142:143, 70:71)
    AMAC(12, 144:145, 146:147, 72:73)
    AMAC(13, 148:149, 150:151, 74:75)
    AMAC(14, 152:153, 154:155, 76:77)
    AMAC(15, 156:157, 158:159, 78:79)
    "s_waitcnt lgkmcnt(0)\n\t"            // xA done (older B-grp done too)
    "v_pk_fma_f32 v[92:93], v[88:89], %[w11P], %[bsP] op_sel:[0,0,0] op_sel_hi:[0,1,1]\n\t"
    "v_pk_fma_f32 v[92:93], v[88:89], %[w21P], v[92:93] op_sel:[1,0,0] op_sel_hi:[1,1,1]\n\t"
    "v_pk_add_f32 v[40:41], v[40:41], v[92:93]\n\t"
    "v_pk_add_f32 v[40:41], v[40:41], v[42:43]\n\t"
    // ---- A tail-head ----
    "v_exp_f32 v80, v40\n\t"
    "v_exp_f32 v81, v41\n\t"
    "v_add_f32 v80, 1.0, v80\n\t"
    "v_add_f32 v81, 1.0, v81\n\t"
    "v_rcp_f32 v80, v80\n\t"
    "v_rcp_f32 v81, v81\n\t"
    "s_nop 1\n\t"
    "v_fma_f32 v80, %[ac1], v80, %[cc1]\n\t"  // g1A
    "ds_bpermute_b32 v82, %[swz], v80\n\t"    // p1A
    "ds_bpermute_b32 v83, %[swz], v81\n\t"    // p2A
    // ---- B: x-selects + MACs (cover A-perm latency) ----
    "ds_bpermute_b32 v90, v33, v26\n\t"       // xB f1
    "ds_bpermute_b32 v91, v33, v27\n\t"       // xB f2
    "v_add_u32 v33, 4, v33\n\t"
    "v_pk_mul_f32 v[44:45], v[96:97], v[160:161] op_sel:[0,0] op_sel_hi:[1,0]\n\t"
    "v_pk_mul_f32 v[46:47], v[98:99], v[160:161] op_sel:[0,1] op_sel_hi:[1,1]\n\t"
    BMAC(1,  100:101, 102:103, 162:163)
    BMAC(2,  104:105, 106:107, 164:165)
    BMAC(3,  108:109, 110:111, 166:167)
    BMAC(4,  112:113, 114:115, 168:169)
    BMAC(5,  116:117, 118:119, 170:171)
    BMAC(6,  120:121, 122:123, 172:173)
    BMAC(7,  124:125, 126:127, 174:175)
    BMAC(8,  128:129, 130:131, 176:177)
    BMAC(9,  132:133, 134:135, 178:179)
    BMAC(10, 136:137, 138:139, 180:181)
    BMAC(11, 140:141, 142:143, 182:183)
    BMAC(12, 144:145, 146:147, 184:185)
    BMAC(13, 148:149, 150:151, 186:187)
    BMAC(14, 152:153, 154:155, 188:189)
    BMAC(15, 156:157, 158:159, 190:191)
    "s_waitcnt lgkmcnt(0)\n\t"            // A-perms + xB done
    "v_pk_fma_f32 v[92:93], v[90:91], %[w11P], %[bsP] op_sel:[0,0,0] op_sel_hi:[0,1,1]\n\t"
    "v_pk_fma_f32 v[92:93], v[90:91], %[w21P], v[92:93] op_sel:[1,0,0] op_sel_hi:[1,1,1]\n\t"
    "v_pk_add_f32 v[44:45], v[44:45], v[92:93]\n\t"
    "v_pk_add_f32 v[44:45], v[44:45], v[46:47]\n\t"
    // ---- braid: A tail-end with B tail-head ----
    "v_mul_f32 v92, v80, v82\n\t"             // g1A*p1A
    "v_fma_f32 %[cA], v81, %[cA], v92\n\t"    // cA
    "v_exp_f32 v84, v44\n\t"                  // B
    "v_exp_f32 v85, v45\n\t"                  // B
    "v_mul_f32 v93, 0xc038aa3b, %[cA]\n\t"
    "v_exp_f32 v93, v93\n\t"
    "v_add_f32 v84, 1.0, v84\n\t"             // B
    "v_add_f32 v85, 1.0, v85\n\t"             // B
    "v_add_f32 v93, 1.0, v93\n\t"
    "v_rcp_f32 v84, v84\n\t"                  // B
    "v_rcp_f32 v85, v85\n\t"                  // B
    "v_rcp_f32 v93, v93\n\t"
    "s_nop 1\n\t"
    "v_fma_f32 v84, %[ac1], v84, %[cc1]\n\t"  // g1B
    "ds_bpermute_b32 v86, %[swz], v84\n\t"    // p1B
    "ds_bpermute_b32 v87, %[swz], v85\n\t"    // p2B
    "v_fma_f32 v93, 2.0, v93, -1.0\n\t"       // tanh(cA)
    "v_mul_f32 %[hA], v83, v93\n\t"           // hA = p2A*tanh(cA)
    "buffer_store_dword %[hA], %[voffA], %[osrd], 0 offen\n\t"
    "v_add_u32 %[voffA], 0xa00, %[voffA]\n\t"
    // ---- A group' (broadcast hA for next step) ----
    "ds_write_b32 %[laddrA], %[hA]\n\t"
    "ds_read_b128 v[48:51], %[hrdA]\n\t"
    "ds_read_b128 v[52:55], %[hrdA] offset:16\n\t"
    "ds_read_b128 v[56:59], %[hrdA] offset:32\n\t"
    "ds_read_b128 v[60:63], %[hrdA] offset:48\n\t"
    "ds_read_b128 v[64:67], %[hrdA] offset:64\n\t"
    "ds_read_b128 v[68:71], %[hrdA] offset:80\n\t"
    "ds_read_b128 v[72:75], %[hrdA] offset:96\n\t"
    "ds_read_b128 v[76:79], %[hrdA] offset:112\n\t"
    "s_waitcnt lgkmcnt(9)\n\t"            // B-perms done (A-grp' in flight)
    // ---- B tail-end ----
    "v_mul_f32 v92, v84, v86\n\t"
    "v_fma_f32 %[cB], v85, %[cB], v92\n\t"
    "v_mul_f32 v93, 0xc038aa3b, %[cB]\n\t"
    "v_exp_f32 v93, v93\n\t"
    "s_nop 1\n\t"
    "v_add_f32 v93, 1.0, v93\n\t"
    "v_rcp_f32 v93, v93\n\t"
    "s_nop 1\n\t"
    "v_fma_f32 v93, 2.0, v93, -1.0\n\t"       // tanh(cB)
    "v_mul_f32 %[hB], v87, v93\n\t"
    "buffer_store_dword %[hB], %[voffB], %[osrd], 0 offen\n\t"
    "v_add_u32 %[voffB], 0xa00, %[voffB]\n\t"
    // ---- B group' ----
    "ds_write_b32 %[laddrB], %[hB]\n\t"
    "ds_read_b128 v[160:163], %[hrdB]\n\t"
    "ds_read_b128 v[164:167], %[hrdB] offset:16\n\t"
    "ds_read_b128 v[168:171], %[hrdB] offset:32\n\t"
    "ds_read_b128 v[172:175], %[hrdB] offset:48\n\t"
    "ds_read_b128 v[176:179], %[hrdB] offset:64\n\t"
    "ds_read_b128 v[180:183], %[hrdB] offset:80\n\t"
    "ds_read_b128 v[184:187], %[hrdB] offset:96\n\t"
    "ds_read_b128 v[188:191], %[hrdB] offset:112\n\t"
    "s_sub_u32 s20, s20, 1\n\t"
    "s_cmp_lg_u32 s20, 0\n\t"
    "s_cbranch_scc1 Lbody%=\n\t"
    // ---- chunk boundary: rotate x, prefetch next ----
    "s_waitcnt vmcnt(0)\n\t"
    "v_mov_b32 v24, v28\n\t"
    "v_mov_b32 v25, v29\n\t"
    "v_mov_b32 v26, v30\n\t"
    "v_mov_b32 v27, v31\n\t"
    "v_add_u32 %[xvA], 0x1000, %[xvA]\n\t"
    "v_add_u32 %[xvB], 0x1000, %[xvB]\n\t"
    "buffer_load_dword v28, %[xvA], %[xsrd], 0 offen\n\t"
    "buffer_load_dword v29, %[xvA], %[xsrd], %[sfd] offen\n\t"
    "buffer_load_dword v30, %[xvB], %[xsrd], 0 offen\n\t"
    "buffer_load_dword v31, %[xvB], %[xsrd], %[sfd] offen\n\t"
    "v_mov_b32 v33, 0\n\t"
    "s_sub_u32 s21, s21, 1\n\t"
    "s_cmp_lg_u32 s21, 0\n\t"
    "s_cbranch_scc1 Louter%=\n\t"
    : [hA]"+v"(hA), [cA]"+v"(cA), [hB]"+v"(hB), [cB]"+v"(cB),
      [voffA]"+v"(voffA), [voffB]"+v"(voffB), [xvA]"+v"(xvA), [xvB]"+v"(xvB)
    : [wrd]"v"(wrd), [laddrA]"v"(laddrA), [hrdA]"v"(hrdA),
      [laddrB]"v"(laddrB), [hrdB]"v"(hrdB), [swz]"v"(swz),
      [w11P]"v"(w11P), [w21P]"v"(w21P), [bsP]"v"(bsP),
      [ac1]"v"(Ac1), [cc1]"v"(Cc1),
      [xsrd]"s"(xsrd), [osrd]"s"(osrd), [sfd]"s"(sfd)
    : "memory", "scc", "s20", "s21",
      "v24","v25","v26","v27","v28","v29","v30","v31","v33",
      "v40","v41","v42","v43","v44","v45","v46","v47",
      "v48","v49","v50","v51","v52","v53","v54","v55",
      "v56","v57","v58","v59","v60","v61","v62","v63",
      "v64","v65","v66","v67","v68","v69","v70","v71",
      "v72","v73","v74","v75","v76","v77","v78","v79",
      "v80","v81","v82","v83","v84","v85","v86","v87",
      "v88","v89","v90","v91","v92","v93",
      "v96","v97","v98","v99","v100","v101","v102","v103",
      "v104","v105","v106","v107","v108","v109","v110","v111",
      "v112","v113","v114","v115","v116","v117","v118","v119",
      "v120","v121","v122","v123","v124","v125","v126","v127",
      "v128","v129","v130","v131","v132","v133","v134","v135",
      "v136","v137","v138","v139","v140","v141","v142","v143",
      "v144","v145","v146","v147","v148","v149","v150","v151",
      "v152","v153","v154","v155","v156","v157","v158","v159",
      "v160","v161","v162","v163","v164","v165","v166","v167",
      "v168","v169","v170","v171","v172","v173","v174","v175",
      "v176","v177","v178","v179","v180","v181","v182","v183",
      "v184","v185","v186","v187","v188","v189","v190","v191");
#undef AMAC
#undef BMAC

  if (lane < 32) {
    out[BN * TT * HN + bA * HN + col] = hA;             // h_t
    out[BN * TT * HN + BN * HN + bA * HN + col] = cA;   // c_t
    out[BN * TT * HN + bB * HN + col] = hB;
    out[BN * TT * HN + BN * HN + bB * HN + col] = cB;
  }
}

extern "C" void kernel_launch(void* const* d_in, const int* in_sizes, int n_in,
                              void* d_out, int out_size, void* d_ws, size_t ws_size,
                              hipStream_t stream) {
  (void)in_sizes; (void)n_in; (void)d_ws; (void)ws_size; (void)out_size;
  const float* x  = (const float*)d_in[0];
  const float* Ui = (const float*)d_in[1];
  const float* Vi = (const float*)d_in[2];
  const float* bi = (const float*)d_in[3];
  const float* Uf = (const float*)d_in[4];
  const float* Vf = (const float*)d_in[5];
  const float* bf = (const float*)d_in[6];
  const float* Uc = (const float*)d_in[7];
  const float* Vc = (const float*)d_in[8];
  const float* bc = (const float*)d_in[9];
  const float* Uo = (const float*)d_in[10];
  const float* Vo = (const float*)d_in[11];
  const float* bo = (const float*)d_in[12];
  float* out = (float*)d_out;

  dim3 grid(1280);  // 20 blocks x 64 batch-pairs; 2 anti-phased units/wave
  dim3 block(64);
  hipLaunchKernelGGL(lstm_kernel, grid, block, 0, stream,
                     x, Ui, Vi, bi, Uf, Vf, bf, Uc, Vc, bc, Uo, Vo, bo, out);
}